// Round 15
// baseline (80.515 us; speedup 1.0000x reference)
//
#include <hip/hip_runtime.h>
#include <math.h>

#define TWO_PI 6.28318530717958647692f
#define NT     1024          // 16 waves per block
#define RPW    4             // cols per wave in FFT phases (64 / 16 waves)
#define PITCH  65            // LDS pitch (odd -> conflict-free both ways)
#define THRESH 10.0f
#define XPITCH 34            // X row pitch per lane (k1 = 0..32, padded to 34)
// e^{2pi i/128} (for k1 = 32 row: e^{2pi i 32/4096})
#define C128   0.998795456205172393f
#define S128   0.049067674327418015f

typedef float v2f __attribute__((ext_vector_type(2)));

__device__ __forceinline__ int brev6(int x) {
    return (int)(__brev((unsigned)x) >> 26);
}

// acc + a*b (complex)
__device__ __forceinline__ v2f cmul_add(v2f a, v2f b, v2f acc) {
    acc += (v2f){a.x, a.x} * b;
    acc += (v2f){a.y, a.y} * (v2f){-b.y, b.x};
    return acc;
}

// Per-lane stage twiddles for the 64-pt cross-lane FFT (6 stages).
struct Tw6 { v2f t[6]; };

__device__ __forceinline__ Tw6 make_tw6(int lane, float sign) {
    Tw6 T;
    #pragma unroll
    for (int s = 0; s < 6; ++s) {
        int h = 1 << s;
        int j = lane & (h - 1);
        float ang = sign * (TWO_PI / 64.0f) * (float)(j * (32 >> s));
        float c, si;
        __sincosf(ang, &si, &c);
        T.t[s] = (v2f){c, si};
    }
    return T;
}

// Cross-lane 64-pt DIF FFT, precomputed twiddles. Natural-order input across
// lanes; output: lane l holds coefficient brev6(l).
template<int R>
__device__ __forceinline__ void fft64_dif_t(float (&re)[R], float (&im)[R],
                                            int lane, const Tw6& T) {
    #pragma unroll
    for (int s = 5; s >= 0; --s) {
        const int h = 1 << s;
        float wr = T.t[s].x, wi = T.t[s].y;
        bool upper = (lane & h) != 0;
        float cwr = upper ? wr : 1.0f;
        float cwi = upper ? wi : 0.0f;
        float sgn = upper ? -1.0f : 1.0f;
        #pragma unroll
        for (int m = 0; m < R; ++m) {
            float orr = __shfl_xor(re[m], h, 64);
            float oii = __shfl_xor(im[m], h, 64);
            float ar = fmaf(sgn, re[m], orr);
            float ai = fmaf(sgn, im[m], oii);
            re[m] = ar * cwr - ai * cwi;
            im[m] = ar * cwi + ai * cwr;
        }
    }
}

// Cross-lane 64-pt DIT FFT, precomputed twiddles. Bit-reversed input across
// lanes; natural-order output.
template<int R>
__device__ __forceinline__ void fft64_dit_t(float (&re)[R], float (&im)[R],
                                            int lane, const Tw6& T) {
    #pragma unroll
    for (int s = 0; s < 6; ++s) {
        const int h = 1 << s;
        float wr = T.t[s].x, wi = T.t[s].y;
        bool upper = (lane & h) != 0;
        float cwr = upper ? wr : 1.0f;
        float cwi = upper ? wi : 0.0f;
        float sgn = upper ? -1.0f : 1.0f;
        #pragma unroll
        for (int m = 0; m < R; ++m) {
            float tr = re[m] * cwr - im[m] * cwi;
            float ti = re[m] * cwi + im[m] * cwr;
            float orr = __shfl_xor(tr, h, 64);
            float oii = __shfl_xor(ti, h, 64);
            re[m] = fmaf(sgn, tr, orr);
            im[m] = fmaf(sgn, ti, oii);
        }
    }
}

// S = sum_q T[q] * u^i v^j  (q = 3i + j), double Horner.
__device__ __forceinline__ v2f tap_combine(const v2f (&T)[9], v2f u, v2f v,
                                           v2f v2) {
    v2f g0 = cmul_add(v2, T[2], cmul_add(v, T[1], T[0]));
    v2f g1 = cmul_add(v2, T[5], cmul_add(v, T[4], T[3]));
    v2f g2 = cmul_add(v2, T[8], cmul_add(v, T[7], T[6]));
    return cmul_add(u, cmul_add(u, g2, g1), g0);
}

// fwd: 256 blocks. Block b: t = b&7 (XCD-pin), r = b>>3, c = r&15, h = r>>4.
// Phase A packs REAL column pairs into one complex FFT, unpacks via
// mirror-lane shuffle. Phase B rows k1<=32 split: h=0 -> 0..15, h=1 ->
// 16..31 + 32. Store TRANSPOSED: X[task][l*XPITCH + k1] = spec[k1+64*brev6(l)]
// so conv can read row pairs as one float4.
__global__ __launch_bounds__(NT) void fwd_kernel(const float* __restrict__ x,
                                                 float2* __restrict__ X) {
    __shared__ float sre[64 * PITCH];
    __shared__ float sim[64 * PITCH];
    const int bId  = blockIdx.x;
    const int t    = bId & 7;
    const int rr_  = bId >> 3;
    const int c    = rr_ & 15;
    const int h    = rr_ >> 4;
    const int task = t * 16 + c;
    const int tid  = threadIdx.x;
    const int lane = tid & 63;
    const int w    = tid >> 6;          // 0..15
    const float* xr = x + (size_t)task * 62 * 62;

    for (int idx = tid; idx < 4096; idx += NT) {
        int r = idx >> 6, s = idx & 63;
        float v = 0.0f;
        if (r >= 1 && r <= 62 && s >= 1 && s <= 62)
            v = xr[(r - 1) * 62 + (s - 1)];
        sre[r * PITCH + s] = v;
    }
    __syncthreads();

    const Tw6 Tf = make_tw6(lane, -1.0f);

    // Phase A (packed): z[p] = col(4w+2p) + i*col(4w+2p+1), lane = n1.
    float zr[2], zi[2];
    #pragma unroll
    for (int p = 0; p < 2; ++p) {
        zr[p] = sre[lane * PITCH + (w * 4 + 2 * p)];
        zi[p] = sre[lane * PITCH + (w * 4 + 2 * p + 1)];
    }
    __syncthreads();                 // input reads done before row overwrite
    fft64_dif_t<2>(zr, zi, lane, Tf);
    const int k1 = brev6(lane);
    const int ml = brev6((64 - k1) & 63);   // lane holding Z[-k1]
    #pragma unroll
    for (int p = 0; p < 2; ++p) {
        float mr = __shfl(zr[p], ml, 64);
        float mi = __shfl(zi[p], ml, 64);
        // FA = (Z + conj(Zm))/2 ; FB = (Z - conj(Zm))/(2i)
        float far = 0.5f * (zr[p] + mr), fai = 0.5f * (zi[p] - mi);
        float fbr = 0.5f * (zi[p] + mi), fbi = 0.5f * (mr - zr[p]);
        int n2a = w * 4 + 2 * p, n2b = n2a + 1;
        float cr, ci;                // midtwiddle e^{-2pi i k1 n2 / 4096}
        __sincosf(-(TWO_PI / 4096.0f) * (float)(k1 * n2a), &ci, &cr);
        sre[k1 * PITCH + n2a] = far * cr - fai * ci;
        sim[k1 * PITCH + n2a] = far * ci + fai * cr;
        __sincosf(-(TWO_PI / 4096.0f) * (float)(k1 * n2b), &ci, &cr);
        sre[k1 * PITCH + n2b] = fbr * cr - fbi * ci;
        sim[k1 * PITCH + n2b] = fbr * ci + fbi * cr;
    }
    __syncthreads();

    // Phase B: 1 row per wave (+ row 32 slot, stored by h=1 wave 0 only).
    float rb[2], ib[2];
    const int row0 = 16 * h + w;
    rb[0] = sre[row0 * PITCH + lane];
    ib[0] = sim[row0 * PITCH + lane];
    rb[1] = sre[32 * PITCH + lane];
    ib[1] = sim[32 * PITCH + lane];
    fft64_dif_t<2>(rb, ib, lane, Tf);
    float2* Xrow = X + (size_t)task * (64 * XPITCH);
    {
        float rv = rb[0], iv = ib[0];
        if (fabsf(rv) < THRESH) { rv = 0.0f; iv = 0.0f; }
        Xrow[lane * XPITCH + row0] = make_float2(rv, iv);  // transposed store
    }
    if (h == 1 && w == 0) {
        float rv = rb[1], iv = ib[1];
        if (fabsf(rv) < THRESH) { rv = 0.0f; iv = 0.0f; }
        Xrow[lane * XPITCH + 32] = make_float2(rv, iv);
    }
}

// conv: block b: t = b&7, o = b>>3. Hermitian tap accumulation (rows 2w,
// 2w+1 loaded as ONE float4 per channel, +row 32 on wave 0), register-resident
// phase-1 DIT; rows 0..32 in LDS; phase 2 packs Hermitian column pairs into
// one complex iFFT (real outputs in re/im); crop + bias.
__global__ __launch_bounds__(NT, 3) void conv_kernel(const float2* __restrict__ X,
                                                     const float* __restrict__ W,
                                                     const float* __restrict__ b,
                                                     float* __restrict__ out) {
    __shared__ float sre[64 * PITCH];
    __shared__ float sim[64 * PITCH];
    const int t    = blockIdx.x & 7;
    const int o    = blockIdx.x >> 3;
    const int tid  = threadIdx.x;
    const int lane = tid & 63;
    const int w    = tid >> 6;          // 0..15

    const int k2 = brev6(lane);
    float elr, eli;          // e^{+2pi i k2/64}
    __sincosf((TWO_PI / 64.0f) * (float)k2, &eli, &elr);

    const Tw6 Ti = make_tw6(lane, +1.0f);

    // Slot twiddles: A: k1=2w, B: k1=2w+1.
    const int rA = 2 * w, rB = 2 * w + 1;
    float uAr, uAi, vAr, vAi, uBr, uBi, vBr, vBi;
    __sincosf((TWO_PI / 64.0f) * (float)rA, &uAi, &uAr);
    __sincosf((TWO_PI / 4096.0f) * (float)rA, &vAi, &vAr);
    __sincosf((TWO_PI / 64.0f) * (float)rB, &uBi, &uBr);
    __sincosf((TWO_PI / 4096.0f) * (float)rB, &vBi, &vBr);
    v2f uA = {uAr, uAi};
    v2f vA = {vAr * elr - vAi * eli, vAr * eli + vAi * elr};
    v2f v2A = {vA.x * vA.x - vA.y * vA.y, 2.0f * vA.x * vA.y};
    v2f uB = {uBr, uBi};
    v2f vB = {vBr * elr - vBi * eli, vBr * eli + vBi * elr};
    v2f v2B = {vB.x * vB.x - vB.y * vB.y, 2.0f * vB.x * vB.y};

    // Per-lane X base: rows 2w (A) and 2w+1 (B) are adjacent -> one float4.
    const float2* Xb = X + (size_t)t * 16 * (64 * XPITCH) + lane * XPITCH;
    const float*  wo = W + o * 144;     // block-uniform -> scalar loads

    // Issue ALL 16 paired loads upfront (one float4 per channel).
    v2f xA[16], xB[16];
    #pragma unroll
    for (int c = 0; c < 16; ++c) {
        const float4* p4 = (const float4*)(Xb + (size_t)c * (64 * XPITCH) + rA);
        float4 q = p4[0];
        xA[c] = (v2f){q.x, q.y};
        xB[c] = (v2f){q.z, q.w};
    }
    // Tap accumulation: T[q] = sum_c W[c,q] * X[c]  (pure FMA, 9 accumulators)
    v2f TA[9], TB[9];
    #pragma unroll
    for (int q = 0; q < 9; ++q) { TA[q] = (v2f){0,0}; TB[q] = (v2f){0,0}; }
    #pragma unroll
    for (int c = 0; c < 16; ++c) {
        const float* wc = wo + c * 9;
        #pragma unroll
        for (int q = 0; q < 9; ++q) {
            float wq = wc[q];
            TA[q] += xA[c] * wq;
            TB[q] += xB[c] * wq;
        }
    }
    v2f SA = tap_combine(TA, uA, vA, v2A);
    v2f SB = tap_combine(TB, uB, vB, v2B);

    // Phase 1 (register-resident): DIT over k2 for own rows only.
    float pr[2] = {SA.x, SB.x};
    float pi[2] = {SA.y, SB.y};
    fft64_dit_t<2>(pr, pi, lane, Ti);   // lane -> n2 (natural order)

    // Mid twiddle per row: * e^{+2pi i n2 k1 / 4096}, n2 = lane.
    {
        float cr, ci;
        __sincosf((TWO_PI / 4096.0f) * (float)(lane * rA), &ci, &cr);
        float rv = pr[0] * cr - pi[0] * ci;
        pi[0]    = pr[0] * ci + pi[0] * cr;
        pr[0]    = rv;
        __sincosf((TWO_PI / 4096.0f) * (float)(lane * rB), &ci, &cr);
        rv    = pr[1] * cr - pi[1] * ci;
        pi[1] = pr[1] * ci + pi[1] * cr;
        pr[1] = rv;
    }

    // Publish own rows (0..32 only; mirrors handled by conj-read in phase 2).
    sre[rA * PITCH + lane] = pr[0]; sim[rA * PITCH + lane] = pi[0];
    sre[rB * PITCH + lane] = pr[1]; sim[rB * PITCH + lane] = pi[1];
    // Row 32 (wave 0): compute, DIT, midtwiddle e^{2pi i lane/128}, store.
    if (w == 0) {
        v2f xC[16];
        #pragma unroll
        for (int c = 0; c < 16; ++c) {
            float2 q = Xb[(size_t)c * (64 * XPITCH) + 32];
            xC[c] = (v2f){q.x, q.y};
        }
        v2f TC[9];
        #pragma unroll
        for (int q = 0; q < 9; ++q) TC[q] = (v2f){0,0};
        #pragma unroll
        for (int c = 0; c < 16; ++c) {
            const float* wc = wo + c * 9;
            #pragma unroll
            for (int q = 0; q < 9; ++q) TC[q] += xC[c] * wc[q];
        }
        v2f vC = {C128 * elr - S128 * eli, C128 * eli + S128 * elr};
        v2f v2C = {vC.x * vC.x - vC.y * vC.y, 2.0f * vC.x * vC.y};
        v2f g0 = cmul_add(v2C, TC[2], cmul_add(vC, TC[1], TC[0]));
        v2f g1 = cmul_add(v2C, TC[5], cmul_add(vC, TC[4], TC[3]));
        v2f g2 = cmul_add(v2C, TC[8], cmul_add(vC, TC[7], TC[6]));
        v2f SC = g0 - g1 + g2;           // u = -1 at k1 = 32
        float cr_[1] = {SC.x}, ci_[1] = {SC.y};
        fft64_dit_t<1>(cr_, ci_, lane, Ti);
        float cr, ci;                    // e^{+2pi i lane*32/4096}
        __sincosf((TWO_PI / 128.0f) * (float)lane, &ci, &cr);
        float rv = cr_[0] * cr - ci_[0] * ci;
        float iv = cr_[0] * ci + ci_[0] * cr;
        sre[32 * PITCH + lane] = rv;
        sim[32 * PITCH + lane] = iv;
    }
    __syncthreads();

    // Phase 2 (packed): Hermitian columns -> real iFFTs, two per complex FFT.
    // P[p] = Z'[:, n2a] + i * Z'[:, n2b]; lane = k1 (rows >32 read as conj).
    const int row  = (lane <= 32) ? lane : 64 - lane;
    const float sg = (lane <= 32) ? 1.0f : -1.0f;
    float yr[2], yi[2];
    #pragma unroll
    for (int p = 0; p < 2; ++p) {
        int n2a = w * 4 + 2 * p, n2b = n2a + 1;
        float ar = sre[row * PITCH + n2a], ai = sg * sim[row * PITCH + n2a];
        float br = sre[row * PITCH + n2b], bi = sg * sim[row * PITCH + n2b];
        yr[p] = ar - bi;
        yi[p] = ai + br;
    }
    fft64_dif_t<2>(yr, yi, lane, Ti);
    __syncthreads();   // phase-2 reads done before y overwrite
    // Lane l holds y[n1 = brev6(l)] for both columns (re/im are the two cols).
    const int n1 = brev6(lane);
    #pragma unroll
    for (int p = 0; p < 2; ++p) {
        int n2a = w * 4 + 2 * p, n2b = n2a + 1;
        sre[n1 * PITCH + n2a] = yr[p];
        sre[n1 * PITCH + n2b] = yi[p];
    }
    __syncthreads();
    const float bias = b[o];
    float* orow = out + (size_t)(t * 32 + o) * 62 * 62;
    for (int idx = tid; idx < 62 * 62; idx += NT) {
        int r = idx / 62, s = idx - r * 62;
        orow[idx] = sre[r * PITCH + s] * (1.0f / 4096.0f) + bias;
    }
}

extern "C" void kernel_launch(void* const* d_in, const int* in_sizes, int n_in,
                              void* d_out, int out_size, void* d_ws, size_t ws_size,
                              hipStream_t stream) {
    const float* x = (const float*)d_in[0];   // (8,16,62,62) f32
    const float* W = (const float*)d_in[1];   // (32,16,3,3)  f32
    const float* b = (const float*)d_in[2];   // (32,)        f32
    float* out = (float*)d_out;               // (8,32,62,62) f32
    float2* X = (float2*)d_ws;                // 128*64*34 float2 = 2.2 MB

    fwd_kernel<<<dim3(256), dim3(NT), 0, stream>>>(x, X);
    conv_kernel<<<dim3(256), dim3(NT), 0, stream>>>(X, W, b, out);
}

// Round 16
// 72.952 us; speedup vs baseline: 1.1037x; 1.1037x over previous
//
#include <hip/hip_runtime.h>
#include <math.h>

#define TWO_PI 6.28318530717958647692f
#define NT     1024          // 16 waves per block
#define RPW    4             // cols per wave in FFT phases (64 / 16 waves)
#define PITCH  65            // LDS pitch (odd -> conflict-free both ways)
#define THRESH 10.0f
// e^{2pi i/128} (for k1 = 32 row: e^{2pi i 32/4096})
#define C128   0.998795456205172393f
#define S128   0.049067674327418015f

typedef float v2f __attribute__((ext_vector_type(2)));

__device__ __forceinline__ int brev6(int x) {
    return (int)(__brev((unsigned)x) >> 26);
}

// acc + a*b (complex)
__device__ __forceinline__ v2f cmul_add(v2f a, v2f b, v2f acc) {
    acc += (v2f){a.x, a.x} * b;
    acc += (v2f){a.y, a.y} * (v2f){-b.y, b.x};
    return acc;
}

// Per-lane stage twiddles for the 64-pt cross-lane FFT (6 stages).
struct Tw6 { v2f t[6]; };

__device__ __forceinline__ Tw6 make_tw6(int lane, float sign) {
    Tw6 T;
    #pragma unroll
    for (int s = 0; s < 6; ++s) {
        int h = 1 << s;
        int j = lane & (h - 1);
        float ang = sign * (TWO_PI / 64.0f) * (float)(j * (32 >> s));
        float c, si;
        __sincosf(ang, &si, &c);
        T.t[s] = (v2f){c, si};
    }
    return T;
}

// Cross-lane 64-pt DIF FFT, precomputed twiddles. Natural-order input across
// lanes; output: lane l holds coefficient brev6(l).
template<int R>
__device__ __forceinline__ void fft64_dif_t(float (&re)[R], float (&im)[R],
                                            int lane, const Tw6& T) {
    #pragma unroll
    for (int s = 5; s >= 0; --s) {
        const int h = 1 << s;
        float wr = T.t[s].x, wi = T.t[s].y;
        bool upper = (lane & h) != 0;
        float cwr = upper ? wr : 1.0f;
        float cwi = upper ? wi : 0.0f;
        float sgn = upper ? -1.0f : 1.0f;
        #pragma unroll
        for (int m = 0; m < R; ++m) {
            float orr = __shfl_xor(re[m], h, 64);
            float oii = __shfl_xor(im[m], h, 64);
            float ar = fmaf(sgn, re[m], orr);
            float ai = fmaf(sgn, im[m], oii);
            re[m] = ar * cwr - ai * cwi;
            im[m] = ar * cwi + ai * cwr;
        }
    }
}

// Cross-lane 64-pt DIT FFT, precomputed twiddles. Bit-reversed input across
// lanes; natural-order output.
template<int R>
__device__ __forceinline__ void fft64_dit_t(float (&re)[R], float (&im)[R],
                                            int lane, const Tw6& T) {
    #pragma unroll
    for (int s = 0; s < 6; ++s) {
        const int h = 1 << s;
        float wr = T.t[s].x, wi = T.t[s].y;
        bool upper = (lane & h) != 0;
        float cwr = upper ? wr : 1.0f;
        float cwi = upper ? wi : 0.0f;
        float sgn = upper ? -1.0f : 1.0f;
        #pragma unroll
        for (int m = 0; m < R; ++m) {
            float tr = re[m] * cwr - im[m] * cwi;
            float ti = re[m] * cwi + im[m] * cwr;
            float orr = __shfl_xor(tr, h, 64);
            float oii = __shfl_xor(ti, h, 64);
            re[m] = fmaf(sgn, tr, orr);
            im[m] = fmaf(sgn, ti, oii);
        }
    }
}

// S = sum_q T[q] * u^i v^j  (q = 3i + j), double Horner.
__device__ __forceinline__ v2f tap_combine(const v2f (&T)[9], v2f u, v2f v,
                                           v2f v2) {
    v2f g0 = cmul_add(v2, T[2], cmul_add(v, T[1], T[0]));
    v2f g1 = cmul_add(v2, T[5], cmul_add(v, T[4], T[3]));
    v2f g2 = cmul_add(v2, T[8], cmul_add(v, T[7], T[6]));
    return cmul_add(u, cmul_add(u, g2, g1), g0);
}

// fwd: 256 blocks. Block b: t = b&7 (XCD-pin), r = b>>3, c = r&15, h = r>>4.
// Phase A packs REAL column pairs into one complex FFT (half the FFTs),
// unpacks via mirror-lane shuffle. Phase B rows k1<=32 split: h=0 -> 0..15,
// h=1 -> 16..31 (+32 on wave 0, as a second R=1 pass).
// Store X[task][k1][l] = spectrum[k1 + 64*brev6(l)]  (lane-coalesced).
__global__ __launch_bounds__(NT) void fwd_kernel(const float* __restrict__ x,
                                                 float2* __restrict__ X) {
    __shared__ float sre[64 * PITCH];
    __shared__ float sim[64 * PITCH];
    const int bId  = blockIdx.x;
    const int t    = bId & 7;
    const int rr_  = bId >> 3;
    const int c    = rr_ & 15;
    const int h    = rr_ >> 4;
    const int task = t * 16 + c;
    const int tid  = threadIdx.x;
    const int lane = tid & 63;
    const int w    = tid >> 6;          // 0..15
    const float* xr = x + (size_t)task * 62 * 62;

    for (int idx = tid; idx < 4096; idx += NT) {
        int r = idx >> 6, s = idx & 63;
        float v = 0.0f;
        if (r >= 1 && r <= 62 && s >= 1 && s <= 62)
            v = xr[(r - 1) * 62 + (s - 1)];
        sre[r * PITCH + s] = v;
    }
    __syncthreads();

    const Tw6 Tf = make_tw6(lane, -1.0f);

    // Phase A (packed): z[p] = col(4w+2p) + i*col(4w+2p+1), lane = n1.
    float zr[2], zi[2];
    #pragma unroll
    for (int p = 0; p < 2; ++p) {
        zr[p] = sre[lane * PITCH + (w * 4 + 2 * p)];
        zi[p] = sre[lane * PITCH + (w * 4 + 2 * p + 1)];
    }
    __syncthreads();                 // input reads done before row overwrite
    fft64_dif_t<2>(zr, zi, lane, Tf);
    const int k1 = brev6(lane);
    const int ml = brev6((64 - k1) & 63);   // lane holding Z[-k1]
    #pragma unroll
    for (int p = 0; p < 2; ++p) {
        float mr = __shfl(zr[p], ml, 64);
        float mi = __shfl(zi[p], ml, 64);
        // FA = (Z + conj(Zm))/2 ; FB = (Z - conj(Zm))/(2i)
        float far = 0.5f * (zr[p] + mr), fai = 0.5f * (zi[p] - mi);
        float fbr = 0.5f * (zi[p] + mi), fbi = 0.5f * (mr - zr[p]);
        int n2a = w * 4 + 2 * p, n2b = n2a + 1;
        float cr, ci;                // midtwiddle e^{-2pi i k1 n2 / 4096}
        __sincosf(-(TWO_PI / 4096.0f) * (float)(k1 * n2a), &ci, &cr);
        sre[k1 * PITCH + n2a] = far * cr - fai * ci;
        sim[k1 * PITCH + n2a] = far * ci + fai * cr;
        __sincosf(-(TWO_PI / 4096.0f) * (float)(k1 * n2b), &ci, &cr);
        sre[k1 * PITCH + n2b] = fbr * cr - fbi * ci;
        sim[k1 * PITCH + n2b] = fbr * ci + fbi * cr;
    }
    __syncthreads();

    // Phase B: 1 row per wave; row 32 handled by (h=1, w=0) as a second pass.
    float2* Xrow = X + (size_t)task * 4096;
    {
        float rb[1], ib[1];
        const int row0 = 16 * h + w;
        rb[0] = sre[row0 * PITCH + lane];
        ib[0] = sim[row0 * PITCH + lane];
        fft64_dif_t<1>(rb, ib, lane, Tf);
        float rv = rb[0], iv = ib[0];
        if (fabsf(rv) < THRESH) { rv = 0.0f; iv = 0.0f; }
        Xrow[row0 * 64 + lane] = make_float2(rv, iv);
    }
    if (h == 1 && w == 0) {
        float rb[1], ib[1];
        rb[0] = sre[32 * PITCH + lane];
        ib[0] = sim[32 * PITCH + lane];
        fft64_dif_t<1>(rb, ib, lane, Tf);
        float rv = rb[0], iv = ib[0];
        if (fabsf(rv) < THRESH) { rv = 0.0f; iv = 0.0f; }
        Xrow[32 * 64 + lane] = make_float2(rv, iv);
    }
}

// conv: block b: t = b&7, o = b>>3. Hermitian tap accumulation (rows 2w,
// 2w+1, +32 on wave 0), register-resident phase-1 DIT; only rows 0..32 kept
// in LDS. Phase 2 packs Hermitian column pairs into one complex iFFT
// (real outputs in re/im); crop + bias.
__global__ __launch_bounds__(NT, 3) void conv_kernel(const float2* __restrict__ X,
                                                     const float* __restrict__ W,
                                                     const float* __restrict__ b,
                                                     float* __restrict__ out) {
    __shared__ float sre[64 * PITCH];
    __shared__ float sim[64 * PITCH];
    const int t    = blockIdx.x & 7;
    const int o    = blockIdx.x >> 3;
    const int tid  = threadIdx.x;
    const int lane = tid & 63;
    const int w    = tid >> 6;          // 0..15

    const int k2 = brev6(lane);
    float elr, eli;          // e^{+2pi i k2/64}
    __sincosf((TWO_PI / 64.0f) * (float)k2, &eli, &elr);

    const Tw6 Ti = make_tw6(lane, +1.0f);

    // Slot twiddles: A: k1=2w, B: k1=2w+1.
    const int rA = 2 * w, rB = 2 * w + 1;
    float uAr, uAi, vAr, vAi, uBr, uBi, vBr, vBi;
    __sincosf((TWO_PI / 64.0f) * (float)rA, &uAi, &uAr);
    __sincosf((TWO_PI / 4096.0f) * (float)rA, &vAi, &vAr);
    __sincosf((TWO_PI / 64.0f) * (float)rB, &uBi, &uBr);
    __sincosf((TWO_PI / 4096.0f) * (float)rB, &vBi, &vBr);
    v2f uA = {uAr, uAi};
    v2f vA = {vAr * elr - vAi * eli, vAr * eli + vAi * elr};
    v2f v2A = {vA.x * vA.x - vA.y * vA.y, 2.0f * vA.x * vA.y};
    v2f uB = {uBr, uBi};
    v2f vB = {vBr * elr - vBi * eli, vBr * eli + vBi * elr};
    v2f v2B = {vB.x * vB.x - vB.y * vB.y, 2.0f * vB.x * vB.y};

    const float2* Xt = X + (size_t)t * 16 * 4096 + lane;
    const float*  wo = W + o * 144;     // block-uniform -> scalar loads

    // Issue ALL 32 loads upfront (16 channels x 2 slots, lane-coalesced).
    v2f xA[16], xB[16];
    #pragma unroll
    for (int c = 0; c < 16; ++c) {
        { float2 q = Xt[c * 4096 + rA * 64]; xA[c] = (v2f){q.x, q.y}; }
        { float2 q = Xt[c * 4096 + rB * 64]; xB[c] = (v2f){q.x, q.y}; }
    }
    // Tap accumulation: T[q] = sum_c W[c,q] * X[c]  (pure FMA, 9 accumulators)
    v2f TA[9], TB[9];
    #pragma unroll
    for (int q = 0; q < 9; ++q) { TA[q] = (v2f){0,0}; TB[q] = (v2f){0,0}; }
    #pragma unroll
    for (int c = 0; c < 16; ++c) {
        const float* wc = wo + c * 9;
        #pragma unroll
        for (int q = 0; q < 9; ++q) {
            float wq = wc[q];
            TA[q] += xA[c] * wq;
            TB[q] += xB[c] * wq;
        }
    }
    v2f SA = tap_combine(TA, uA, vA, v2A);
    v2f SB = tap_combine(TB, uB, vB, v2B);

    // Phase 1 (register-resident): DIT over k2 for own rows only.
    float pr[2] = {SA.x, SB.x};
    float pi[2] = {SA.y, SB.y};
    fft64_dit_t<2>(pr, pi, lane, Ti);   // lane -> n2 (natural order)

    // Mid twiddle per row: * e^{+2pi i n2 k1 / 4096}, n2 = lane.
    {
        float cr, ci;
        __sincosf((TWO_PI / 4096.0f) * (float)(lane * rA), &ci, &cr);
        float rv = pr[0] * cr - pi[0] * ci;
        pi[0]    = pr[0] * ci + pi[0] * cr;
        pr[0]    = rv;
        __sincosf((TWO_PI / 4096.0f) * (float)(lane * rB), &ci, &cr);
        rv    = pr[1] * cr - pi[1] * ci;
        pi[1] = pr[1] * ci + pi[1] * cr;
        pr[1] = rv;
    }

    // Publish own rows (0..32 only; mirrors handled by conj-read in phase 2).
    sre[rA * PITCH + lane] = pr[0]; sim[rA * PITCH + lane] = pi[0];
    sre[rB * PITCH + lane] = pr[1]; sim[rB * PITCH + lane] = pi[1];
    // Row 32 (wave 0): compute, DIT, midtwiddle e^{2pi i lane/128}, store.
    if (w == 0) {
        v2f xC[16];
        #pragma unroll
        for (int c = 0; c < 16; ++c) {
            float2 q = Xt[c * 4096 + 32 * 64]; xC[c] = (v2f){q.x, q.y};
        }
        v2f TC[9];
        #pragma unroll
        for (int q = 0; q < 9; ++q) TC[q] = (v2f){0,0};
        #pragma unroll
        for (int c = 0; c < 16; ++c) {
            const float* wc = wo + c * 9;
            #pragma unroll
            for (int q = 0; q < 9; ++q) TC[q] += xC[c] * wc[q];
        }
        v2f vC = {C128 * elr - S128 * eli, C128 * eli + S128 * elr};
        v2f v2C = {vC.x * vC.x - vC.y * vC.y, 2.0f * vC.x * vC.y};
        v2f g0 = cmul_add(v2C, TC[2], cmul_add(vC, TC[1], TC[0]));
        v2f g1 = cmul_add(v2C, TC[5], cmul_add(vC, TC[4], TC[3]));
        v2f g2 = cmul_add(v2C, TC[8], cmul_add(vC, TC[7], TC[6]));
        v2f SC = g0 - g1 + g2;           // u = -1 at k1 = 32
        float cr_[1] = {SC.x}, ci_[1] = {SC.y};
        fft64_dit_t<1>(cr_, ci_, lane, Ti);
        float cr, ci;                    // e^{+2pi i lane*32/4096}
        __sincosf((TWO_PI / 128.0f) * (float)lane, &ci, &cr);
        float rv = cr_[0] * cr - ci_[0] * ci;
        float iv = cr_[0] * ci + ci_[0] * cr;
        sre[32 * PITCH + lane] = rv;
        sim[32 * PITCH + lane] = iv;
    }
    __syncthreads();

    // Phase 2 (packed): Hermitian columns -> real iFFTs, two per complex FFT.
    // P[p] = Z'[:, n2a] + i * Z'[:, n2b]; lane = k1 (rows >32 read as conj).
    const int row  = (lane <= 32) ? lane : 64 - lane;
    const float sg = (lane <= 32) ? 1.0f : -1.0f;
    float yr[2], yi[2];
    #pragma unroll
    for (int p = 0; p < 2; ++p) {
        int n2a = w * 4 + 2 * p, n2b = n2a + 1;
        float ar = sre[row * PITCH + n2a], ai = sg * sim[row * PITCH + n2a];
        float br = sre[row * PITCH + n2b], bi = sg * sim[row * PITCH + n2b];
        yr[p] = ar - bi;
        yi[p] = ai + br;
    }
    fft64_dif_t<2>(yr, yi, lane, Ti);
    __syncthreads();   // phase-2 reads done before y overwrite
    // Lane l holds y[n1 = brev6(l)] for both columns (re/im are the two cols).
    const int n1 = brev6(lane);
    #pragma unroll
    for (int p = 0; p < 2; ++p) {
        int n2a = w * 4 + 2 * p, n2b = n2a + 1;
        sre[n1 * PITCH + n2a] = yr[p];
        sre[n1 * PITCH + n2b] = yi[p];
    }
    __syncthreads();
    const float bias = b[o];
    float* orow = out + (size_t)(t * 32 + o) * 62 * 62;
    for (int idx = tid; idx < 62 * 62; idx += NT) {
        int r = idx / 62, s = idx - r * 62;
        orow[idx] = sre[r * PITCH + s] * (1.0f / 4096.0f) + bias;
    }
}

extern "C" void kernel_launch(void* const* d_in, const int* in_sizes, int n_in,
                              void* d_out, int out_size, void* d_ws, size_t ws_size,
                              hipStream_t stream) {
    const float* x = (const float*)d_in[0];   // (8,16,62,62) f32
    const float* W = (const float*)d_in[1];   // (32,16,3,3)  f32
    const float* b = (const float*)d_in[2];   // (32,)        f32
    float* out = (float*)d_out;               // (8,32,62,62) f32
    float2* X = (float2*)d_ws;                // 128*4096 complex = 4 MB

    fwd_kernel<<<dim3(256), dim3(NT), 0, stream>>>(x, X);
    conv_kernel<<<dim3(256), dim3(NT), 0, stream>>>(X, W, b, out);
}